// Round 8
// baseline (2714.676 us; speedup 1.0000x reference)
//
#include <hip/hip_runtime.h>
#include <math.h>

#define DIM 128
#define THRESH 0.1f
#define COS_EPSF 1e-8f
#define LN_EPSF 1e-5f

// ---------- lane helpers ----------
__device__ __forceinline__ float red8_sum(float v) {
  v += __shfl_xor(v, 1); v += __shfl_xor(v, 2); v += __shfl_xor(v, 4);
  return v;
}
__device__ __forceinline__ float red8_max(float v) {
  v = fmaxf(v, __shfl_xor(v, 1)); v = fmaxf(v, __shfl_xor(v, 2));
  v = fmaxf(v, __shfl_xor(v, 4));
  return v;
}
__device__ __forceinline__ float4 sh4(float4 v, int m) {
  return make_float4(__shfl_xor(v.x, m), __shfl_xor(v.y, m),
                     __shfl_xor(v.z, m), __shfl_xor(v.w, m));
}
__device__ __forceinline__ float4 add4(float4 a, float4 b) {
  return make_float4(a.x + b.x, a.y + b.y, a.z + b.z, a.w + b.w);
}

// ---------------- CSR build ----------------
__global__ void hist_k(const int* __restrict__ row, int* __restrict__ fill, int E) {
  int e = blockIdx.x * blockDim.x + threadIdx.x;
  if (e < E) atomicAdd(&fill[row[e]], 1);
}

__global__ void scan1_k(const int* __restrict__ in, int* __restrict__ out,
                        int* __restrict__ part, int n) {
  __shared__ int sm[1024];
  int gid = blockIdx.x * 1024 + threadIdx.x;
  int v = (gid < n) ? in[gid] : 0;
  sm[threadIdx.x] = v;
  __syncthreads();
  for (int off = 1; off < 1024; off <<= 1) {
    int t = (threadIdx.x >= off) ? sm[threadIdx.x - off] : 0;
    __syncthreads();
    sm[threadIdx.x] += t;
    __syncthreads();
  }
  if (gid < n) out[gid] = sm[threadIdx.x] - v;  // exclusive
  if (threadIdx.x == 1023) part[blockIdx.x] = sm[1023];
}

__global__ void scan2_k(int* __restrict__ part, int nparts) {
  __shared__ int sm[1024];
  int v = (threadIdx.x < nparts) ? part[threadIdx.x] : 0;
  sm[threadIdx.x] = v;
  __syncthreads();
  for (int off = 1; off < 1024; off <<= 1) {
    int t = (threadIdx.x >= off) ? sm[threadIdx.x - off] : 0;
    __syncthreads();
    sm[threadIdx.x] += t;
    __syncthreads();
  }
  if (threadIdx.x < nparts) part[threadIdx.x] = sm[threadIdx.x] - v;
}

// setE >= 0: also write out[n] = setE (used for CSR1 where total is known host-side)
__global__ void scan3_k(int* __restrict__ out, const int* __restrict__ part, int n, int setE) {
  int gid = blockIdx.x * 1024 + threadIdx.x;
  if (gid < n) out[gid] += part[blockIdx.x];
  if (gid == 0 && setE >= 0) out[n] = setE;
}

__global__ void fix_k(int* __restrict__ rp2, const int* __restrict__ alive, int n) {
  rp2[n] = rp2[n - 1] + alive[n - 1];
}

__global__ void scatter_k(const int* __restrict__ row, const int* __restrict__ col,
                          const int* __restrict__ row_ptr, int* __restrict__ fill,
                          int* __restrict__ csr_col, int E) {
  int e = blockIdx.x * blockDim.x + threadIdx.x;
  if (e < E) {
    int r = row[e];
    int p = row_ptr[r] + atomicAdd(&fill[r], 1);
    csr_col[p] = col[e];
  }
}

// ---------------- per-node norms of x (layer 1 only) ----------------
__global__ void norm_k(const float* __restrict__ F, float* __restrict__ nrm, int n) {
  int wid = threadIdx.x >> 6, lane = threadIdx.x & 63;
  int r = blockIdx.x * 4 + wid;
  if (r >= n) return;
  float2 v = ((const float2*)(F + (size_t)r * DIM))[lane];
  float s = v.x * v.x + v.y * v.y;
  for (int o = 32; o > 0; o >>= 1) s += __shfl_xor(s, o);
  if (lane == 0) nrm[r] = fmaxf(sqrtf(s), COS_EPSF);
}

// ---------------- sims pass: 8 lanes/edge, 8 edges per wave iteration ----------------
// FIRST: full CSR, writes s_eff + alive_cnt. else: compacted CSR2, updates s2 in place.
template <bool FIRST>
__global__ void sims_k(const float* __restrict__ F, const float* __restrict__ nrm,
                       const int* __restrict__ rp, const int* __restrict__ colA,
                       float* __restrict__ sA, float* __restrict__ dinv,
                       int* __restrict__ cnt, int* __restrict__ alive_cnt, int n) {
  int wid = threadIdx.x >> 6, lane = threadIdx.x & 63;
  int r = blockIdx.x * 4 + wid;
  if (r >= n) return;
  int sl = lane & 7, g = lane >> 3;   // 8 groups of 8 lanes
  const float4* Fr = (const float4*)(F + (size_t)r * DIM);
  float4 fr0 = Fr[sl * 4], fr1 = Fr[sl * 4 + 1], fr2 = Fr[sl * 4 + 2], fr3 = Fr[sl * 4 + 3];
  float nr = nrm[r];
  int beg = rp[r], end = rp[r + 1];
  float deg = 0.f;
  int ac = 0;
  for (int e0 = beg; e0 < end; e0 += 8) {
    int e = e0 + g;
    bool act = e < end;                       // uniform within 8-lane group
    bool alive = act;
    if (!FIRST) alive = act && (sA[e] > 0.f); // group-uniform load
    float se = 0.f;
    int c = -1;
    if (alive) {
      c = colA[e];
      const float4* Fc = (const float4*)(F + (size_t)c * DIM);
      float4 c0 = Fc[sl * 4], c1 = Fc[sl * 4 + 1], c2 = Fc[sl * 4 + 2], c3 = Fc[sl * 4 + 3];
      float d = fr0.x * c0.x + fr0.y * c0.y + fr0.z * c0.z + fr0.w * c0.w +
                fr1.x * c1.x + fr1.y * c1.y + fr1.z * c1.z + fr1.w * c1.w +
                fr2.x * c2.x + fr2.y * c2.y + fr2.z * c2.z + fr2.w * c2.w +
                fr3.x * c3.x + fr3.y * c3.y + fr3.z * c3.z + fr3.w * c3.w;
      d = red8_sum(d);                        // group-uniform branch: safe shuffles
      float s = d / (nr * nrm[c]);
      if (s >= THRESH) se = s;
    }
    if (act && sl == 0) {
      sA[e] = se;
      if (se > 0.f) atomicAdd(&cnt[c], 1);
    }
    deg += se;                                // se uniform in group
    if (FIRST) ac += (se > 0.f) ? 1 : 0;
  }
  deg += __shfl_xor(deg, 8); deg += __shfl_xor(deg, 16); deg += __shfl_xor(deg, 32);
  if (lane == 0) dinv[r] = (deg > 0.f) ? (1.0f / sqrtf(deg)) : 0.f;
  if (FIRST) {
    ac += __shfl_xor(ac, 8); ac += __shfl_xor(ac, 16); ac += __shfl_xor(ac, 32);
    if (lane == 0) alive_cnt[r] = ac;
  }
}

// ---------------- compact alive edges of CSR -> CSR2 ----------------
__global__ void compact_k(const int* __restrict__ rp, const int* __restrict__ csr_col,
                          const float* __restrict__ s_eff, const int* __restrict__ rp2,
                          int* __restrict__ col2, float* __restrict__ s2, int n) {
  int wid = threadIdx.x >> 6, lane = threadIdx.x & 63;
  int r = blockIdx.x * 4 + wid;
  if (r >= n) return;
  int beg = rp[r], end = rp[r + 1];
  int base = rp2[r];
  for (int e0 = beg; e0 < end; e0 += 64) {
    int e = e0 + lane;
    float s = 0.f;
    bool a = false;
    if (e < end) { s = s_eff[e]; a = s > 0.f; }
    unsigned long long m = __ballot(a);
    int pos = base + __popcll(m & ((1ull << lane) - 1ull));
    if (a) { col2[pos] = csr_col[e]; s2[pos] = s; }
    base += __popcll(m);
  }
}

// ---------------- GEMM: G[n,128] = F[n,128] @ W[128,128] ----------------
// 128x128 tile / block, 256 threads, 8x8 register tile per thread.
// K split in 4 phases of 32: LDS = Fs[128][36] + Ws[32][128] = 34.4 KB -> 3 blocks/CU.
// In-place safe: block writes only rows it staged.
__global__ __launch_bounds__(256, 3) void gemm_k(const float* __restrict__ F,
                                                 const float* __restrict__ W,
                                                 float* __restrict__ G, int n) {
  __shared__ float Fs[128 * 36];   // row r at r*36 (32 k + 4 pad)
  __shared__ float Ws[32 * 128];   // Ws[k_local*128 + c]
  int t = threadIdx.x;
  int tx = t & 15;                  // cols tx*4..+3 and tx*4+64..+67
  int w = t >> 6;                   // wave 0..3 -> rows 32w..32w+31
  int sub = (t >> 4) & 3;           // sub-row: thread rows = 32w + sub + 4i, i=0..7
  int r0 = blockIdx.x * 128;
  int rows = n - r0; if (rows > 128) rows = 128;

  float acc[8][8];
#pragma unroll
  for (int i = 0; i < 8; ++i)
#pragma unroll
    for (int j = 0; j < 8; ++j) acc[i][j] = 0.f;

  const float4* W4 = (const float4*)W;
  const float4* F4 = (const float4*)(F + (size_t)r0 * DIM);

  for (int p = 0; p < 4; ++p) {
    // stage W quarter: k = 32p..32p+31, all 128 cols (1024 float4, 4/thread)
    {
      float4* Ws4 = (float4*)Ws;
#pragma unroll
      for (int jj = 0; jj < 4; ++jj) {
        int j = t + 256 * jj;
        Ws4[j] = W4[p * 1024 + j];
      }
    }
    // stage F quarter: rows x 32 k (rows*8 float4)
    for (int j = t; j < rows * 8; j += 256) {
      int rr = j >> 3, kq = j & 7;
      *(float4*)(&Fs[rr * 36 + kq * 4]) = F4[rr * 32 + p * 8 + kq];
    }
    __syncthreads();

#pragma unroll
    for (int kq = 0; kq < 8; ++kq) {
      float4 wA[4], wB[4];
#pragma unroll
      for (int q = 0; q < 4; ++q) {
        int k = kq * 4 + q;
        wA[q] = *(const float4*)(&Ws[k * 128 + tx * 4]);
        wB[q] = *(const float4*)(&Ws[k * 128 + tx * 4 + 64]);
      }
#pragma unroll
      for (int i = 0; i < 8; ++i) {
        int rr = 32 * w + sub + 4 * i;
        float4 f = *(const float4*)(&Fs[rr * 36 + kq * 4]);
        acc[i][0] += f.x * wA[0].x + f.y * wA[1].x + f.z * wA[2].x + f.w * wA[3].x;
        acc[i][1] += f.x * wA[0].y + f.y * wA[1].y + f.z * wA[2].y + f.w * wA[3].y;
        acc[i][2] += f.x * wA[0].z + f.y * wA[1].z + f.z * wA[2].z + f.w * wA[3].z;
        acc[i][3] += f.x * wA[0].w + f.y * wA[1].w + f.z * wA[2].w + f.w * wA[3].w;
        acc[i][4] += f.x * wB[0].x + f.y * wB[1].x + f.z * wB[2].x + f.w * wB[3].x;
        acc[i][5] += f.x * wB[0].y + f.y * wB[1].y + f.z * wB[2].y + f.w * wB[3].y;
        acc[i][6] += f.x * wB[0].z + f.y * wB[1].z + f.z * wB[2].z + f.w * wB[3].z;
        acc[i][7] += f.x * wB[0].w + f.y * wB[1].w + f.z * wB[2].w + f.w * wB[3].w;
      }
    }
    __syncthreads();
  }

#pragma unroll
  for (int i = 0; i < 8; ++i) {
    int r = r0 + 32 * w + sub + 4 * i;
    if (r < n) {
      float* out = G + (size_t)r * DIM + tx * 4;
      *(float4*)out = make_float4(acc[i][0], acc[i][1], acc[i][2], acc[i][3]);
      *(float4*)(out + 64) = make_float4(acc[i][4], acc[i][5], acc[i][6], acc[i][7]);
    }
  }
}

// ---------------- fused SpMM (CSR2) + self term + bias + (LN+ReLU+nrm | log_softmax) ----
// 8 lanes/edge, 8 edges in flight; lane sl holds cols sl*16..sl*16+15 (4 float4).
template <int MODE>
__global__ void spmm_k(const float* __restrict__ G, const float* __restrict__ s2,
                       const int* __restrict__ col2, const float* __restrict__ dinv,
                       const int* __restrict__ cnt, float selfoff,
                       const int* __restrict__ rp2, const float* __restrict__ bias,
                       const float* __restrict__ gam, const float* __restrict__ bet,
                       float* __restrict__ out, float* __restrict__ nrm, int n) {
  int wid = threadIdx.x >> 6, lane = threadIdx.x & 63;
  int r = blockIdx.x * 4 + wid;
  if (r >= n) return;
  int sl = lane & 7, g = lane >> 3;
  float4 a0 = make_float4(0.f, 0.f, 0.f, 0.f), a1 = a0, a2 = a0, a3 = a0;
  if (g == 0) {
    float vs = expf(1.0f / ((float)cnt[r] + selfoff));
    const float4* Gr = (const float4*)(G + (size_t)r * DIM);
    float4 g0 = Gr[sl * 4], g1 = Gr[sl * 4 + 1], g2 = Gr[sl * 4 + 2], g3 = Gr[sl * 4 + 3];
    a0 = make_float4(vs * g0.x, vs * g0.y, vs * g0.z, vs * g0.w);
    a1 = make_float4(vs * g1.x, vs * g1.y, vs * g1.z, vs * g1.w);
    a2 = make_float4(vs * g2.x, vs * g2.y, vs * g2.z, vs * g2.w);
    a3 = make_float4(vs * g3.x, vs * g3.y, vs * g3.z, vs * g3.w);
  }
  float dr = dinv[r];
  int beg = rp2[r], end = rp2[r + 1];
  for (int e0 = beg; e0 < end; e0 += 8) {
    int e = e0 + g;
    bool act = e < end;
    float s = act ? s2[e] : 0.f;              // group-uniform
    if (s > 0.f) {
      int c = col2[e];
      float v = expf(dr * s * dinv[c]);
      const float4* Gc = (const float4*)(G + (size_t)c * DIM);
      float4 c0 = Gc[sl * 4], c1 = Gc[sl * 4 + 1], c2 = Gc[sl * 4 + 2], c3 = Gc[sl * 4 + 3];
      a0 = make_float4(a0.x + v * c0.x, a0.y + v * c0.y, a0.z + v * c0.z, a0.w + v * c0.w);
      a1 = make_float4(a1.x + v * c1.x, a1.y + v * c1.y, a1.z + v * c1.z, a1.w + v * c1.w);
      a2 = make_float4(a2.x + v * c2.x, a2.y + v * c2.y, a2.z + v * c2.z, a2.w + v * c2.w);
      a3 = make_float4(a3.x + v * c3.x, a3.y + v * c3.y, a3.z + v * c3.z, a3.w + v * c3.w);
    }
  }
  a0 = add4(a0, sh4(a0, 8)); a0 = add4(a0, sh4(a0, 16)); a0 = add4(a0, sh4(a0, 32));
  a1 = add4(a1, sh4(a1, 8)); a1 = add4(a1, sh4(a1, 16)); a1 = add4(a1, sh4(a1, 32));
  a2 = add4(a2, sh4(a2, 8)); a2 = add4(a2, sh4(a2, 16)); a2 = add4(a2, sh4(a2, 32));
  a3 = add4(a3, sh4(a3, 8)); a3 = add4(a3, sh4(a3, 16)); a3 = add4(a3, sh4(a3, 32));
  const float4* B4 = (const float4*)bias;
  a0 = add4(a0, B4[sl * 4]); a1 = add4(a1, B4[sl * 4 + 1]);
  a2 = add4(a2, B4[sl * 4 + 2]); a3 = add4(a3, B4[sl * 4 + 3]);
  if (MODE == 0) {
    float lsum = a0.x + a0.y + a0.z + a0.w + a1.x + a1.y + a1.z + a1.w +
                 a2.x + a2.y + a2.z + a2.w + a3.x + a3.y + a3.z + a3.w;
    float mu = red8_sum(lsum) * (1.0f / DIM);
    float4 d0 = make_float4(a0.x - mu, a0.y - mu, a0.z - mu, a0.w - mu);
    float4 d1 = make_float4(a1.x - mu, a1.y - mu, a1.z - mu, a1.w - mu);
    float4 d2 = make_float4(a2.x - mu, a2.y - mu, a2.z - mu, a2.w - mu);
    float4 d3 = make_float4(a3.x - mu, a3.y - mu, a3.z - mu, a3.w - mu);
    float lvar = d0.x * d0.x + d0.y * d0.y + d0.z * d0.z + d0.w * d0.w +
                 d1.x * d1.x + d1.y * d1.y + d1.z * d1.z + d1.w * d1.w +
                 d2.x * d2.x + d2.y * d2.y + d2.z * d2.z + d2.w * d2.w +
                 d3.x * d3.x + d3.y * d3.y + d3.z * d3.z + d3.w * d3.w;
    float var = red8_sum(lvar) * (1.0f / DIM);
    float is = 1.0f / sqrtf(var + LN_EPSF);
    const float4* G4 = (const float4*)gam;
    const float4* Be4 = (const float4*)bet;
    float4 h[4];
    float ns = 0.f;
    float4 dd[4] = {d0, d1, d2, d3};
#pragma unroll
    for (int q = 0; q < 4; ++q) {
      float4 gm = G4[sl * 4 + q], be = Be4[sl * 4 + q];
      h[q] = make_float4(fmaxf(dd[q].x * is * gm.x + be.x, 0.f),
                         fmaxf(dd[q].y * is * gm.y + be.y, 0.f),
                         fmaxf(dd[q].z * is * gm.z + be.z, 0.f),
                         fmaxf(dd[q].w * is * gm.w + be.w, 0.f));
      ns += h[q].x * h[q].x + h[q].y * h[q].y + h[q].z * h[q].z + h[q].w * h[q].w;
    }
    if (lane < 8) {
      float4* O4 = (float4*)(out + (size_t)r * DIM);
#pragma unroll
      for (int q = 0; q < 4; ++q) O4[sl * 4 + q] = h[q];
    }
    ns = red8_sum(ns);
    if (lane == 0) nrm[r] = fmaxf(sqrtf(ns), COS_EPSF);
  } else {
    float mx = fmaxf(fmaxf(fmaxf(a0.x, a0.y), fmaxf(a0.z, a0.w)),
                     fmaxf(fmaxf(a1.x, a1.y), fmaxf(a1.z, a1.w)));
    mx = fmaxf(mx, fmaxf(fmaxf(fmaxf(a2.x, a2.y), fmaxf(a2.z, a2.w)),
                         fmaxf(fmaxf(a3.x, a3.y), fmaxf(a3.z, a3.w))));
    mx = red8_max(mx);
    float se = expf(a0.x - mx) + expf(a0.y - mx) + expf(a0.z - mx) + expf(a0.w - mx) +
               expf(a1.x - mx) + expf(a1.y - mx) + expf(a1.z - mx) + expf(a1.w - mx) +
               expf(a2.x - mx) + expf(a2.y - mx) + expf(a2.z - mx) + expf(a2.w - mx) +
               expf(a3.x - mx) + expf(a3.y - mx) + expf(a3.z - mx) + expf(a3.w - mx);
    float ls = logf(red8_sum(se)) + mx;
    if (lane < 8) {
      float4* O4 = (float4*)(out + (size_t)r * DIM);
      O4[sl * 4]     = make_float4(a0.x - ls, a0.y - ls, a0.z - ls, a0.w - ls);
      O4[sl * 4 + 1] = make_float4(a1.x - ls, a1.y - ls, a1.z - ls, a1.w - ls);
      O4[sl * 4 + 2] = make_float4(a2.x - ls, a2.y - ls, a2.z - ls, a2.w - ls);
      O4[sl * 4 + 3] = make_float4(a3.x - ls, a3.y - ls, a3.z - ls, a3.w - ls);
    }
  }
}

extern "C" void kernel_launch(void* const* d_in, const int* in_sizes, int n_in,
                              void* d_out, int out_size, void* d_ws, size_t ws_size,
                              hipStream_t stream) {
  const float* x  = (const float*)d_in[0];
  const int* row  = (const int*)d_in[1];
  const int* col  = (const int*)d_in[2];
  const float* W0 = (const float*)d_in[3];
  const float* b0 = (const float*)d_in[4];
  const float* W1 = (const float*)d_in[5];
  const float* b1 = (const float*)d_in[6];
  const float* g1 = (const float*)d_in[7];
  const float* be1 = (const float*)d_in[8];
  const float* g2 = (const float*)d_in[9];
  const float* be2 = (const float*)d_in[10];
  int n = in_sizes[0] / DIM;
  int E = in_sizes[1];
  float* outp = (float*)d_out;

  char* w = (char*)d_ws;
  size_t off = 0;
  auto alloc = [&](size_t bytes) {
    char* p = w + off;
    off = (off + bytes + 255) & ~(size_t)255;
    return p;
  };
  int* row_ptr   = (int*)alloc((size_t)(n + 1) * 4);
  int* rp2       = (int*)alloc((size_t)(n + 1) * 4);
  int* fill      = (int*)alloc((size_t)n * 4);
  int* cnt       = (int*)alloc((size_t)n * 4);
  int* alive_cnt = (int*)alloc((size_t)n * 4);
  int* part      = (int*)alloc(1024 * 4);
  float* dinv    = (float*)alloc((size_t)n * 4);
  float* nrm     = (float*)alloc((size_t)n * 4);
  int* col2      = (int*)alloc((size_t)E * 4);
  float* s2      = (float*)alloc((size_t)E * 4);
  // Union region: full-CSR buffers (csr_col, s_eff) are dead after compact_k,
  // strictly before B1's first write (same stream) -> B1 aliases them.
  size_t mark = off;
  int* csr_col   = (int*)alloc((size_t)E * 4);
  float* s_eff   = (float*)alloc((size_t)E * 4);
  off = mark;
  float* B1      = (float*)alloc((size_t)n * DIM * 4);
  (void)ws_size; (void)n_in; (void)out_size;

  int eb = (E + 255) / 256;
  int nch = (n + 1023) / 1024;
  int rb = (n + 3) / 4;       // wave-per-row kernels
  int gb = (n + 127) / 128;   // gemm blocks

  // ---- CSR build ----
  hipMemsetAsync(fill, 0, (size_t)n * 4, stream);
  hipLaunchKernelGGL(hist_k, dim3(eb), dim3(256), 0, stream, row, fill, E);
  hipLaunchKernelGGL(scan1_k, dim3(nch), dim3(1024), 0, stream, fill, row_ptr, part, n);
  hipLaunchKernelGGL(scan2_k, dim3(1), dim3(1024), 0, stream, part, nch);
  hipLaunchKernelGGL(scan3_k, dim3(nch), dim3(1024), 0, stream, row_ptr, part, n, E);
  hipMemsetAsync(fill, 0, (size_t)n * 4, stream);
  hipLaunchKernelGGL(scatter_k, dim3(eb), dim3(256), 0, stream, row, col, row_ptr, fill, csr_col, E);

  // ---- layer 1 sims on full CSR ----
  hipLaunchKernelGGL(norm_k, dim3(rb), dim3(256), 0, stream, x, nrm, n);
  hipMemsetAsync(cnt, 0, (size_t)n * 4, stream);
  hipLaunchKernelGGL(sims_k<true>, dim3(rb), dim3(256), 0, stream,
                     x, nrm, row_ptr, csr_col, s_eff, dinv, cnt, alive_cnt, n);

  // ---- compact alive edges -> CSR2 ----
  hipLaunchKernelGGL(scan1_k, dim3(nch), dim3(1024), 0, stream, alive_cnt, rp2, part, n);
  hipLaunchKernelGGL(scan2_k, dim3(1), dim3(1024), 0, stream, part, nch);
  hipLaunchKernelGGL(scan3_k, dim3(nch), dim3(1024), 0, stream, rp2, part, n, -1);
  hipLaunchKernelGGL(fix_k, dim3(1), dim3(1), 0, stream, rp2, alive_cnt, n);
  hipLaunchKernelGGL(compact_k, dim3(rb), dim3(256), 0, stream,
                     row_ptr, csr_col, s_eff, rp2, col2, s2, n);

  // ---- layer 1: gemm + spmm ----
  hipLaunchKernelGGL(gemm_k, dim3(gb), dim3(256), 0, stream, x, W0, outp, n);
  hipLaunchKernelGGL(spmm_k<0>, dim3(rb), dim3(256), 0, stream,
                     outp, s2, col2, dinv, cnt, 1.0f, rp2, b0, g1, be1, B1, nrm, n);

  // ---- layer 2 ----
  hipMemsetAsync(cnt, 0, (size_t)n * 4, stream);
  hipLaunchKernelGGL(sims_k<false>, dim3(rb), dim3(256), 0, stream,
                     B1, nrm, rp2, col2, s2, dinv, cnt, (int*)nullptr, n);
  hipLaunchKernelGGL(gemm_k, dim3(gb), dim3(256), 0, stream, B1, W1, B1, n);  // in-place safe
  hipLaunchKernelGGL(spmm_k<0>, dim3(rb), dim3(256), 0, stream,
                     B1, s2, col2, dinv, cnt, 2.0f, rp2, b1, g2, be2, outp, nrm, n);

  // ---- layer 3 (reuses W1/b1; log_softmax) ----
  hipMemsetAsync(cnt, 0, (size_t)n * 4, stream);
  hipLaunchKernelGGL(sims_k<false>, dim3(rb), dim3(256), 0, stream,
                     outp, nrm, rp2, col2, s2, dinv, cnt, (int*)nullptr, n);
  hipLaunchKernelGGL(gemm_k, dim3(gb), dim3(256), 0, stream, outp, W1, B1, n);
  hipLaunchKernelGGL(spmm_k<1>, dim3(rb), dim3(256), 0, stream,
                     B1, s2, col2, dinv, cnt, 2.0f, rp2, b1, b1, b1, outp, nrm, n);
}